// Round 2
// baseline (1399.644 us; speedup 1.0000x reference)
//
#include <hip/hip_runtime.h>
#include <hip/hip_bf16.h>

#define NTHREADS 256

// ---------------- degree + count: one fused edge pass ----------------

__global__ void deg_init_k(float* deg, int* counts, int n) {
    int i = blockIdx.x * blockDim.x + threadIdx.x;
    if (i < n) { deg[i] = 1.0f; counts[i] = 0; }   // self-loop weight 1
}

__global__ void edge_pass1_k(const int* __restrict__ row, const int* __restrict__ col,
                             const float* __restrict__ w, float* deg, int* counts, int e) {
    int i = blockIdx.x * blockDim.x + threadIdx.x;
    if (i < e) {
        atomicAdd(&deg[row[i]], w[i]);
        atomicAdd(&counts[col[i]], 1);
    }
}

__global__ void dinv_k(float* deg, int n) {
    int i = blockIdx.x * blockDim.x + threadIdx.x;
    if (i < n) deg[i] = rsqrtf(fmaxf(deg[i], 1e-12f));   // in-place: deg -> dinv
}

// ---------------- CSR build (by destination col) ----------------

__global__ void scan1_k(const int* __restrict__ counts, int* offsets, int* blockSums, int n) {
    __shared__ int s[256];
    int tid = threadIdx.x;
    int idx = blockIdx.x * 256 + tid;
    int v = (idx < n) ? counts[idx] : 0;
    s[tid] = v;
    __syncthreads();
    for (int off = 1; off < 256; off <<= 1) {
        int t = (tid >= off) ? s[tid - off] : 0;
        __syncthreads();
        s[tid] += t;
        __syncthreads();
    }
    if (idx < n) offsets[idx] = s[tid] - v;        // local exclusive
    if (tid == 255) blockSums[blockIdx.x] = s[255]; // block total
}

__global__ void scan2_k(int* blockSums, int nb) {
    __shared__ int s[1024];
    int tid = threadIdx.x;
    int v = (tid < nb) ? blockSums[tid] : 0;
    s[tid] = v;
    __syncthreads();
    for (int off = 1; off < 1024; off <<= 1) {
        int t = (tid >= off) ? s[tid - off] : 0;
        __syncthreads();
        s[tid] += t;
        __syncthreads();
    }
    if (tid < nb) blockSums[tid] = s[tid] - v;      // exclusive
}

__global__ void scan3_k(int* offsets, const int* __restrict__ blockSums, int* cursor,
                        int n, int total) {
    int idx = blockIdx.x * blockDim.x + threadIdx.x;
    if (idx < n) {
        offsets[idx] += blockSums[idx >> 8];
        cursor[idx] = 0;
    }
    if (idx == n) offsets[n] = total;
}

__global__ void scatter_k(const int* __restrict__ row, const int* __restrict__ col,
                          const float* __restrict__ w, const float* __restrict__ dinv,
                          const int* __restrict__ offsets, int* cursor,
                          int2* csr, int e) {
    int i = blockIdx.x * blockDim.x + threadIdx.x;
    if (i >= e) return;
    int r = row[i], c = col[i];
    int pos = offsets[c] + atomicAdd(&cursor[c], 1);
    float nw = dinv[r] * w[i] * dinv[c];
    csr[pos] = make_int2(r, __float_as_int(nw));
}

// ---------------- x -> bf16 seed (z0 = x) ----------------

__global__ void tobf16_k(const float* __restrict__ x, __hip_bfloat16* __restrict__ z,
                         int total) {
    int i = blockIdx.x * blockDim.x + threadIdx.x;
    if (i < total) z[i] = __float2bfloat16(x[i]);
}

// ---------------- Horner propagation: one wave per node ----------------
// MODE 0: z_out = bf16( x + A * z_in )
// MODE 1: y     = 0.09f * (A * z_in) + 0.1f * x        (final, fp32)

template <int MODE>
__global__ __launch_bounds__(256) void horner_k(
    const __hip_bfloat16* __restrict__ z_in,
    __hip_bfloat16* __restrict__ z_out,
    float* __restrict__ y,
    const float* __restrict__ x,
    const float* __restrict__ dinv,
    const int* __restrict__ offsets,
    const int2* __restrict__ csr,
    int n)
{
    int node = blockIdx.x * 4 + (threadIdx.x >> 6);
    if (node >= n) return;
    int t = threadIdx.x & 63;
    size_t o = (size_t)node * 64 + t;
    float di = dinv[node];
    float sum = di * di * __bfloat162float(z_in[o]);   // self-loop term
    int beg = offsets[node], end = offsets[node + 1];
    for (int j = beg; j < end; ++j) {
        int2 sw = csr[j];
        float v = __bfloat162float(z_in[(size_t)sw.x * 64 + t]);
        sum = fmaf(__int_as_float(sw.y), v, sum);
    }
    if (MODE == 0) {
        z_out[o] = __float2bfloat16(x[o] + sum);
    } else {
        y[o] = 0.09f * sum + 0.1f * x[o];
    }
}

// ---------------- MLP epilogue: y @ W0 relu @ W1 ----------------

__global__ __launch_bounds__(256) void mlp_k(const float* __restrict__ y,
                                             const float* __restrict__ W0,
                                             const float* __restrict__ b0,
                                             const float* __restrict__ W1,
                                             const float* __restrict__ b1,
                                             float* __restrict__ out, int n) {
    __shared__ float W0s[64 * 64];
    __shared__ float W1s[64 * 32];
    __shared__ float b0s[64];
    __shared__ float b1s[32];
    __shared__ float z[32][64];
    __shared__ float hid[32][64];
    int tid = threadIdx.x;
    for (int i = tid; i < 64 * 64; i += 256) W0s[i] = W0[i];
    for (int i = tid; i < 64 * 32; i += 256) W1s[i] = W1[i];
    if (tid < 64) b0s[tid] = b0[tid];
    else if (tid < 96) b1s[tid - 64] = b1[tid - 64];

    int base = blockIdx.x * 32;
    for (int r = 0; r < 8; ++r) {
        int idx = r * 256 + tid;
        int nn = idx >> 6, f = idx & 63;
        int node = base + nn;
        z[nn][f] = (node < n) ? y[(size_t)node * 64 + f] : 0.f;
    }
    __syncthreads();
    for (int r = 0; r < 8; ++r) {
        int idx = r * 256 + tid;
        int nn = idx >> 6, j = idx & 63;
        float s = b0s[j];
#pragma unroll
        for (int i = 0; i < 64; ++i) s += z[nn][i] * W0s[i * 64 + j];
        hid[nn][j] = fmaxf(s, 0.f);
    }
    __syncthreads();
    for (int r = 0; r < 4; ++r) {
        int idx = r * 256 + tid;
        int nn = idx >> 5, o = idx & 31;
        int node = base + nn;
        if (node >= n) continue;
        float s = b1s[o];
#pragma unroll
        for (int i = 0; i < 64; ++i) s += hid[nn][i] * W1s[i * 32 + o];
        out[(size_t)node * 32 + o] = s;
    }
}

// ---------------- launch ----------------

extern "C" void kernel_launch(void* const* d_in, const int* in_sizes, int n_in,
                              void* d_out, int out_size, void* d_ws, size_t ws_size,
                              hipStream_t stream) {
    const float* x   = (const float*)d_in[0];
    const int*   ei  = (const int*)d_in[1];
    const float* ew  = (const float*)d_in[2];
    const float* W0  = (const float*)d_in[3];
    const float* b0  = (const float*)d_in[4];
    const float* W1  = (const float*)d_in[5];
    const float* b1  = (const float*)d_in[6];
    float* out = (float*)d_out;

    const int N = in_sizes[0] / 64;   // 100000
    const int E = in_sizes[2];        // 1200000
    const int* row = ei;
    const int* col = ei + E;

    char* p = (char*)d_ws;
    auto alloc = [&](size_t bytes) -> void* {
        void* r = (void*)p;
        p += (bytes + 255) & ~(size_t)255;
        return r;
    };
    float* dinv      = (float*)alloc((size_t)N * 4);
    int*   counts    = (int*)alloc((size_t)N * 4);       // reused as scatter cursor
    int*   offsets   = (int*)alloc((size_t)(N + 1) * 4);
    int    nb        = (N + 255) / 256;
    int*   blockSums = (int*)alloc((size_t)nb * 4);
    int2*  csr       = (int2*)alloc((size_t)E * 8);
    __hip_bfloat16* z0 = (__hip_bfloat16*)alloc((size_t)N * 64 * 2);
    __hip_bfloat16* z1 = (__hip_bfloat16*)alloc((size_t)N * 64 * 2);
    float* yv        = (float*)alloc((size_t)N * 64 * 4);

    int gN = (N + NTHREADS - 1) / NTHREADS;
    int gE = (E + NTHREADS - 1) / NTHREADS;

    deg_init_k<<<gN, NTHREADS, 0, stream>>>(dinv, counts, N);
    edge_pass1_k<<<gE, NTHREADS, 0, stream>>>(row, col, ew, dinv, counts, E);
    dinv_k<<<gN, NTHREADS, 0, stream>>>(dinv, N);

    scan1_k<<<nb, 256, 0, stream>>>(counts, offsets, blockSums, N);
    scan2_k<<<1, 1024, 0, stream>>>(blockSums, nb);
    scan3_k<<<(N + 1 + NTHREADS - 1) / NTHREADS, NTHREADS, 0, stream>>>(offsets, blockSums,
                                                                        counts, N, E);
    scatter_k<<<gE, NTHREADS, 0, stream>>>(row, col, ew, dinv, offsets, counts, csr, E);

    // z0 = bf16(x)
    tobf16_k<<<(N * 64 + NTHREADS - 1) / NTHREADS, NTHREADS, 0, stream>>>(x, z0, N * 64);

    // 9 Horner steps: z_j = bf16(x + A z_{j-1})
    int gP = (N + 3) / 4;
    __hip_bfloat16* zi = z0;
    __hip_bfloat16* zo = z1;
    for (int k = 1; k <= 9; ++k) {
        horner_k<0><<<gP, 256, 0, stream>>>(zi, zo, nullptr, x, dinv, offsets, csr, N);
        __hip_bfloat16* tmp = zi; zi = zo; zo = tmp;
    }
    // final: y = 0.09 * (A z_9) + 0.1 * x
    horner_k<1><<<gP, 256, 0, stream>>>(zi, nullptr, yv, x, dinv, offsets, csr, N);

    mlp_k<<<(N + 31) / 32, 256, 0, stream>>>(yv, W0, b0, W1, b1, out, N);
}

// Round 3
// 673.692 us; speedup vs baseline: 2.0776x; 2.0776x over previous
//
#include <hip/hip_runtime.h>
#include <hip/hip_bf16.h>

#define NTHREADS 256

typedef unsigned int uint32;
typedef unsigned short ushort16;

// ---------------- bf16 helpers ----------------

__device__ __forceinline__ float blo(uint32 u) { return __uint_as_float(u << 16); }
__device__ __forceinline__ float bhi(uint32 u) { return __uint_as_float(u & 0xffff0000u); }

__device__ __forceinline__ unsigned short bf16bits(float f) {
    __hip_bfloat16 h = __float2bfloat16(f);
    return *reinterpret_cast<unsigned short*>(&h);
}
__device__ __forceinline__ uint32 pk2(float a, float b) {
    return (uint32)bf16bits(a) | ((uint32)bf16bits(b) << 16);
}

// ---------------- degree + count: one fused edge pass ----------------

__global__ void deg_init_k(float* deg, int* counts, int n) {
    int i = blockIdx.x * blockDim.x + threadIdx.x;
    if (i < n) { deg[i] = 1.0f; counts[i] = 0; }   // self-loop weight 1
}

__global__ void edge_pass1_k(const int* __restrict__ row, const int* __restrict__ col,
                             const float* __restrict__ w, float* deg, int* counts, int e) {
    int i = blockIdx.x * blockDim.x + threadIdx.x;
    if (i < e) {
        atomicAdd(&deg[row[i]], w[i]);
        atomicAdd(&counts[col[i]], 1);
    }
}

__global__ void dinv_k(float* deg, int n) {
    int i = blockIdx.x * blockDim.x + threadIdx.x;
    if (i < n) deg[i] = rsqrtf(fmaxf(deg[i], 1e-12f));   // in-place: deg -> dinv
}

// ---------------- CSR build (by destination col) ----------------

__global__ void scan1_k(const int* __restrict__ counts, int* offsets, int* blockSums, int n) {
    __shared__ int s[256];
    int tid = threadIdx.x;
    int idx = blockIdx.x * 256 + tid;
    int v = (idx < n) ? counts[idx] : 0;
    s[tid] = v;
    __syncthreads();
    for (int off = 1; off < 256; off <<= 1) {
        int t = (tid >= off) ? s[tid - off] : 0;
        __syncthreads();
        s[tid] += t;
        __syncthreads();
    }
    if (idx < n) offsets[idx] = s[tid] - v;
    if (tid == 255) blockSums[blockIdx.x] = s[255];
}

__global__ void scan2_k(int* blockSums, int nb) {
    __shared__ int s[1024];
    int tid = threadIdx.x;
    int v = (tid < nb) ? blockSums[tid] : 0;
    s[tid] = v;
    __syncthreads();
    for (int off = 1; off < 1024; off <<= 1) {
        int t = (tid >= off) ? s[tid - off] : 0;
        __syncthreads();
        s[tid] += t;
        __syncthreads();
    }
    if (tid < nb) blockSums[tid] = s[tid] - v;
}

__global__ void scan3_k(int* offsets, const int* __restrict__ blockSums, int* cursor,
                        int n, int total) {
    int idx = blockIdx.x * blockDim.x + threadIdx.x;
    if (idx < n) {
        offsets[idx] += blockSums[idx >> 8];
        cursor[idx] = 0;
    }
    if (idx == n) offsets[n] = total;
}

__global__ void scatter_k(const int* __restrict__ row, const int* __restrict__ col,
                          const float* __restrict__ w, const float* __restrict__ dinv,
                          const int* __restrict__ offsets, int* cursor,
                          int2* csr, int e) {
    int i = blockIdx.x * blockDim.x + threadIdx.x;
    if (i >= e) return;
    int r = row[i], c = col[i];
    int pos = offsets[c] + atomicAdd(&cursor[c], 1);
    float nw = dinv[r] * w[i] * dinv[c];
    csr[pos] = make_int2(r, __float_as_int(nw));
}

// ---------------- x -> bf16 seed ----------------

__global__ void tobf16_k(const float* __restrict__ x, unsigned short* __restrict__ z,
                         int total) {
    int i = blockIdx.x * blockDim.x + threadIdx.x;
    if (i < total) z[i] = bf16bits(x[i]);
}

// ---------------- Horner propagation: one wave per node, 8 edges/iter ----------------
// Wave layout: 8 groups (g = lane>>3) x 8 lanes (s = lane&7).
// Group g handles edge beg+it*8+g; lane s loads 16B = features s*8..s*8+7 (bf16).
// MODE 0: z_out = bf16( x_bf + A * z_in )
// MODE 1: y     = 0.09f * (A * z_in) + 0.1f * x   (fp32)

template <int MODE>
__global__ __launch_bounds__(256) void horner8_k(
    const unsigned short* __restrict__ z_in,
    unsigned short* __restrict__ z_out,
    float* __restrict__ y,
    const unsigned short* __restrict__ x_bf,
    const float* __restrict__ x,
    const float* __restrict__ dinv,
    const int* __restrict__ offsets,
    const int2* __restrict__ csr,
    int n)
{
    int node = blockIdx.x * 4 + (threadIdx.x >> 6);
    if (node >= n) return;
    int lane = threadIdx.x & 63;
    int g = lane >> 3;   // edge group
    int s = lane & 7;    // 16B slice of the row

    float acc0 = 0.f, acc1 = 0.f, acc2 = 0.f, acc3 = 0.f;
    float acc4 = 0.f, acc5 = 0.f, acc6 = 0.f, acc7 = 0.f;

    int beg = offsets[node], end = offsets[node + 1];
    for (int base = beg; base < end; base += 8) {
        int j = base + g;
        int2 sw = (j < end) ? csr[j] : make_int2(0, 0);   // w=0 for pad lanes
        float w = __int_as_float(sw.y);
        const uint4* prow = (const uint4*)(z_in + (size_t)sw.x * 64);
        uint4 q = prow[s];
        acc0 = fmaf(w, blo(q.x), acc0);
        acc1 = fmaf(w, bhi(q.x), acc1);
        acc2 = fmaf(w, blo(q.y), acc2);
        acc3 = fmaf(w, bhi(q.y), acc3);
        acc4 = fmaf(w, blo(q.z), acc4);
        acc5 = fmaf(w, bhi(q.z), acc5);
        acc6 = fmaf(w, blo(q.w), acc6);
        acc7 = fmaf(w, bhi(q.w), acc7);
    }
    // butterfly reduce across the 8 groups (lane bits 3,4,5)
#pragma unroll
    for (int mask = 8; mask <= 32; mask <<= 1) {
        acc0 += __shfl_xor(acc0, mask);
        acc1 += __shfl_xor(acc1, mask);
        acc2 += __shfl_xor(acc2, mask);
        acc3 += __shfl_xor(acc3, mask);
        acc4 += __shfl_xor(acc4, mask);
        acc5 += __shfl_xor(acc5, mask);
        acc6 += __shfl_xor(acc6, mask);
        acc7 += __shfl_xor(acc7, mask);
    }

    if (g == 0) {   // lanes 0..7 finish the row
        float di = dinv[node];
        float dd = di * di;
        uint4 zq = ((const uint4*)(z_in + (size_t)node * 64))[s];   // self row slice
        acc0 = fmaf(dd, blo(zq.x), acc0);
        acc1 = fmaf(dd, bhi(zq.x), acc1);
        acc2 = fmaf(dd, blo(zq.y), acc2);
        acc3 = fmaf(dd, bhi(zq.y), acc3);
        acc4 = fmaf(dd, blo(zq.z), acc4);
        acc5 = fmaf(dd, bhi(zq.z), acc5);
        acc6 = fmaf(dd, blo(zq.w), acc6);
        acc7 = fmaf(dd, bhi(zq.w), acc7);
        if (MODE == 0) {
            uint4 xq = ((const uint4*)(x_bf + (size_t)node * 64))[s];
            uint4 o;
            o.x = pk2(acc0 + blo(xq.x), acc1 + bhi(xq.x));
            o.y = pk2(acc2 + blo(xq.y), acc3 + bhi(xq.y));
            o.z = pk2(acc4 + blo(xq.z), acc5 + bhi(xq.z));
            o.w = pk2(acc6 + blo(xq.w), acc7 + bhi(xq.w));
            ((uint4*)(z_out + (size_t)node * 64))[s] = o;
        } else {
            const float4* xr = (const float4*)(x + (size_t)node * 64);
            float4 xa = xr[s * 2], xb = xr[s * 2 + 1];
            float4* yr = (float4*)(y + (size_t)node * 64);
            yr[s * 2]     = make_float4(fmaf(0.09f, acc0, 0.1f * xa.x),
                                        fmaf(0.09f, acc1, 0.1f * xa.y),
                                        fmaf(0.09f, acc2, 0.1f * xa.z),
                                        fmaf(0.09f, acc3, 0.1f * xa.w));
            yr[s * 2 + 1] = make_float4(fmaf(0.09f, acc4, 0.1f * xb.x),
                                        fmaf(0.09f, acc5, 0.1f * xb.y),
                                        fmaf(0.09f, acc6, 0.1f * xb.z),
                                        fmaf(0.09f, acc7, 0.1f * xb.w));
        }
    }
}

// ---------------- MLP epilogue: y @ W0 relu @ W1 ----------------

__global__ __launch_bounds__(256) void mlp_k(const float* __restrict__ y,
                                             const float* __restrict__ W0,
                                             const float* __restrict__ b0,
                                             const float* __restrict__ W1,
                                             const float* __restrict__ b1,
                                             float* __restrict__ out, int n) {
    __shared__ float W0s[64 * 64];
    __shared__ float W1s[64 * 32];
    __shared__ float b0s[64];
    __shared__ float b1s[32];
    __shared__ float z[32][64];
    __shared__ float hid[32][64];
    int tid = threadIdx.x;
    for (int i = tid; i < 64 * 64; i += 256) W0s[i] = W0[i];
    for (int i = tid; i < 64 * 32; i += 256) W1s[i] = W1[i];
    if (tid < 64) b0s[tid] = b0[tid];
    else if (tid < 96) b1s[tid - 64] = b1[tid - 64];

    int base = blockIdx.x * 32;
    for (int r = 0; r < 8; ++r) {
        int idx = r * 256 + tid;
        int nn = idx >> 6, f = idx & 63;
        int node = base + nn;
        z[nn][f] = (node < n) ? y[(size_t)node * 64 + f] : 0.f;
    }
    __syncthreads();
    for (int r = 0; r < 8; ++r) {
        int idx = r * 256 + tid;
        int nn = idx >> 6, j = idx & 63;
        float s = b0s[j];
#pragma unroll
        for (int i = 0; i < 64; ++i) s += z[nn][i] * W0s[i * 64 + j];
        hid[nn][j] = fmaxf(s, 0.f);
    }
    __syncthreads();
    for (int r = 0; r < 4; ++r) {
        int idx = r * 256 + tid;
        int nn = idx >> 5, o = idx & 31;
        int node = base + nn;
        if (node >= n) continue;
        float s = b1s[o];
#pragma unroll
        for (int i = 0; i < 64; ++i) s += hid[nn][i] * W1s[i * 32 + o];
        out[(size_t)node * 32 + o] = s;
    }
}

// ---------------- launch ----------------

extern "C" void kernel_launch(void* const* d_in, const int* in_sizes, int n_in,
                              void* d_out, int out_size, void* d_ws, size_t ws_size,
                              hipStream_t stream) {
    const float* x   = (const float*)d_in[0];
    const int*   ei  = (const int*)d_in[1];
    const float* ew  = (const float*)d_in[2];
    const float* W0  = (const float*)d_in[3];
    const float* b0  = (const float*)d_in[4];
    const float* W1  = (const float*)d_in[5];
    const float* b1  = (const float*)d_in[6];
    float* out = (float*)d_out;

    const int N = in_sizes[0] / 64;   // 100000
    const int E = in_sizes[2];        // 1200000
    const int* row = ei;
    const int* col = ei + E;

    char* p = (char*)d_ws;
    auto alloc = [&](size_t bytes) -> void* {
        void* r = (void*)p;
        p += (bytes + 255) & ~(size_t)255;
        return r;
    };
    float* dinv      = (float*)alloc((size_t)N * 4);
    int*   counts    = (int*)alloc((size_t)N * 4);       // reused as scatter cursor
    int*   offsets   = (int*)alloc((size_t)(N + 1) * 4);
    int    nb        = (N + 255) / 256;
    int*   blockSums = (int*)alloc((size_t)nb * 4);
    int2*  csr       = (int2*)alloc((size_t)E * 8);
    unsigned short* xbf = (unsigned short*)alloc((size_t)N * 64 * 2);  // bf16(x) == z0
    unsigned short* zA  = (unsigned short*)alloc((size_t)N * 64 * 2);
    unsigned short* zB  = (unsigned short*)alloc((size_t)N * 64 * 2);
    float* yv        = (float*)alloc((size_t)N * 64 * 4);

    int gN = (N + NTHREADS - 1) / NTHREADS;
    int gE = (E + NTHREADS - 1) / NTHREADS;

    deg_init_k<<<gN, NTHREADS, 0, stream>>>(dinv, counts, N);
    edge_pass1_k<<<gE, NTHREADS, 0, stream>>>(row, col, ew, dinv, counts, E);
    dinv_k<<<gN, NTHREADS, 0, stream>>>(dinv, N);

    scan1_k<<<nb, 256, 0, stream>>>(counts, offsets, blockSums, N);
    scan2_k<<<1, 1024, 0, stream>>>(blockSums, nb);
    scan3_k<<<(N + 1 + NTHREADS - 1) / NTHREADS, NTHREADS, 0, stream>>>(offsets, blockSums,
                                                                        counts, N, E);
    scatter_k<<<gE, NTHREADS, 0, stream>>>(row, col, ew, dinv, offsets, counts, csr, E);

    tobf16_k<<<(N * 64 + NTHREADS - 1) / NTHREADS, NTHREADS, 0, stream>>>(x, xbf, N * 64);

    // 9 Horner steps: z_j = bf16(x + A z_{j-1}); first input is xbf (= z0)
    int gP = (N + 3) / 4;
    const unsigned short* zi = xbf;
    unsigned short* zo = zA;
    unsigned short* znext = zB;
    for (int k = 1; k <= 9; ++k) {
        horner8_k<0><<<gP, 256, 0, stream>>>(zi, zo, nullptr, xbf, x, dinv, offsets, csr, N);
        zi = zo;
        zo = znext;
        znext = (unsigned short*)zi == zA ? zB : zA;
        zo = (zi == zA) ? zB : zA;
    }
    // final: y = 0.09 * (A z_9) + 0.1 * x
    horner8_k<1><<<gP, 256, 0, stream>>>(zi, nullptr, yv, xbf, x, dinv, offsets, csr, N);

    mlp_k<<<(N + 31) / 32, 256, 0, stream>>>(yv, W0, b0, W1, b1, out, N);
}

// Round 4
// 625.813 us; speedup vs baseline: 2.2365x; 1.0765x over previous
//
#include <hip/hip_runtime.h>
#include <hip/hip_bf16.h>

#define NTHREADS 256

typedef unsigned int uint32;

// ---------------- bf16 helpers ----------------

__device__ __forceinline__ float blo(uint32 u) { return __uint_as_float(u << 16); }
__device__ __forceinline__ float bhi(uint32 u) { return __uint_as_float(u & 0xffff0000u); }

__device__ __forceinline__ unsigned short bf16bits(float f) {
    __hip_bfloat16 h = __float2bfloat16(f);
    return *reinterpret_cast<unsigned short*>(&h);
}
__device__ __forceinline__ uint32 pk2(float a, float b) {
    return (uint32)bf16bits(a) | ((uint32)bf16bits(b) << 16);
}

// ---------------- degree + count + slot: one fused edge pass ----------------

__global__ void deg_init_k(float* deg, int* counts, int n) {
    int i = blockIdx.x * blockDim.x + threadIdx.x;
    if (i < n) { deg[i] = 1.0f; counts[i] = 0; }   // self-loop weight 1
}

__global__ void edge_pass1_k(const int* __restrict__ row, const int* __restrict__ col,
                             const float* __restrict__ w, float* deg, int* counts,
                             int* __restrict__ pos, int e) {
    int i = blockIdx.x * blockDim.x + threadIdx.x;
    if (i < e) {
        atomicAdd(&deg[row[i]], w[i]);
        pos[i] = atomicAdd(&counts[col[i]], 1);   // slot within destination node
    }
}

__global__ void dinv_k(float* deg, int n) {
    int i = blockIdx.x * blockDim.x + threadIdx.x;
    if (i < n) deg[i] = rsqrtf(fmaxf(deg[i], 1e-12f));   // in-place: deg -> dinv
}

// ---------------- CSR offsets (scan over counts) ----------------

__global__ void scan1_k(const int* __restrict__ counts, int* offsets, int* blockSums, int n) {
    __shared__ int s[256];
    int tid = threadIdx.x;
    int idx = blockIdx.x * 256 + tid;
    int v = (idx < n) ? counts[idx] : 0;
    s[tid] = v;
    __syncthreads();
    for (int off = 1; off < 256; off <<= 1) {
        int t = (tid >= off) ? s[tid - off] : 0;
        __syncthreads();
        s[tid] += t;
        __syncthreads();
    }
    if (idx < n) offsets[idx] = s[tid] - v;
    if (tid == 255) blockSums[blockIdx.x] = s[255];
}

__global__ void scan2_k(int* blockSums, int nb) {
    __shared__ int s[1024];
    int tid = threadIdx.x;
    int v = (tid < nb) ? blockSums[tid] : 0;
    s[tid] = v;
    __syncthreads();
    for (int off = 1; off < 1024; off <<= 1) {
        int t = (tid >= off) ? s[tid - off] : 0;
        __syncthreads();
        s[tid] += t;
        __syncthreads();
    }
    if (tid < nb) blockSums[tid] = s[tid] - v;
}

__global__ void scan3_k(int* offsets, const int* __restrict__ blockSums, int n, int total) {
    int idx = blockIdx.x * blockDim.x + threadIdx.x;
    if (idx < n) offsets[idx] += blockSums[idx >> 8];
    if (idx == n) offsets[n] = total;
}

// ---------------- atomic-free scatter ----------------

__global__ void scatter_k(const int* __restrict__ row, const int* __restrict__ col,
                          const float* __restrict__ w, const float* __restrict__ dinv,
                          const int* __restrict__ offsets, const int* __restrict__ pos,
                          int2* __restrict__ csr, int e) {
    int i = blockIdx.x * blockDim.x + threadIdx.x;
    if (i >= e) return;
    int r = row[i], c = col[i];
    int p = offsets[c] + pos[i];
    float nw = dinv[r] * w[i] * dinv[c];
    csr[p] = make_int2(r, __float_as_int(nw));
}

// ---------------- x -> bf16 seed ----------------

__global__ void tobf16_k(const float* __restrict__ x, unsigned short* __restrict__ z,
                         int total) {
    int i = blockIdx.x * blockDim.x + threadIdx.x;
    if (i < total) z[i] = bf16bits(x[i]);
}

// ---------------- Horner propagation: one wave per node, 16 edges in flight ----------------
// Wave layout: 8 groups (g = lane>>3) x 8 lanes (s = lane&7).
// Group g handles edges base+g and base+8+g; lane s loads 16B = features s*8..s*8+7.
// Pad lanes get w=0 and gather row 0 (always cache-hot) -> free.
// MODE 0: z_out = bf16( x_bf + A * z_in )
// MODE 1: y     = 0.09f * (A * z_in) + 0.1f * x   (fp32)

template <int MODE>
__global__ __launch_bounds__(256) void horner8_k(
    const unsigned short* __restrict__ z_in,
    unsigned short* __restrict__ z_out,
    float* __restrict__ y,
    const unsigned short* __restrict__ x_bf,
    const float* __restrict__ x,
    const float* __restrict__ dinv,
    const int* __restrict__ offsets,
    const int2* __restrict__ csr,
    int n)
{
    int node = blockIdx.x * 4 + (threadIdx.x >> 6);
    if (node >= n) return;
    int lane = threadIdx.x & 63;
    int g = lane >> 3;   // edge group
    int s = lane & 7;    // 16B slice of the row

    float acc0 = 0.f, acc1 = 0.f, acc2 = 0.f, acc3 = 0.f;
    float acc4 = 0.f, acc5 = 0.f, acc6 = 0.f, acc7 = 0.f;

    int beg = offsets[node], end = offsets[node + 1];
    for (int base = beg; base < end; base += 16) {
        int j0 = base + g;
        int j1 = base + 8 + g;
        int2 sw0 = (j0 < end) ? csr[j0] : make_int2(0, 0);
        int2 sw1 = (j1 < end) ? csr[j1] : make_int2(0, 0);
        float w0 = __int_as_float(sw0.y);
        float w1 = __int_as_float(sw1.y);
        uint4 q0 = ((const uint4*)(z_in + (size_t)sw0.x * 64))[s];
        uint4 q1 = ((const uint4*)(z_in + (size_t)sw1.x * 64))[s];
        acc0 = fmaf(w0, blo(q0.x), acc0);
        acc1 = fmaf(w0, bhi(q0.x), acc1);
        acc2 = fmaf(w0, blo(q0.y), acc2);
        acc3 = fmaf(w0, bhi(q0.y), acc3);
        acc4 = fmaf(w0, blo(q0.z), acc4);
        acc5 = fmaf(w0, bhi(q0.z), acc5);
        acc6 = fmaf(w0, blo(q0.w), acc6);
        acc7 = fmaf(w0, bhi(q0.w), acc7);
        acc0 = fmaf(w1, blo(q1.x), acc0);
        acc1 = fmaf(w1, bhi(q1.x), acc1);
        acc2 = fmaf(w1, blo(q1.y), acc2);
        acc3 = fmaf(w1, bhi(q1.y), acc3);
        acc4 = fmaf(w1, blo(q1.z), acc4);
        acc5 = fmaf(w1, bhi(q1.z), acc5);
        acc6 = fmaf(w1, blo(q1.w), acc6);
        acc7 = fmaf(w1, bhi(q1.w), acc7);
    }
    // butterfly reduce across the 8 groups (lane bits 3,4,5)
#pragma unroll
    for (int mask = 8; mask <= 32; mask <<= 1) {
        acc0 += __shfl_xor(acc0, mask);
        acc1 += __shfl_xor(acc1, mask);
        acc2 += __shfl_xor(acc2, mask);
        acc3 += __shfl_xor(acc3, mask);
        acc4 += __shfl_xor(acc4, mask);
        acc5 += __shfl_xor(acc5, mask);
        acc6 += __shfl_xor(acc6, mask);
        acc7 += __shfl_xor(acc7, mask);
    }

    if (g == 0) {   // lanes 0..7 finish the row
        float di = dinv[node];
        float dd = di * di;
        uint4 zq = ((const uint4*)(z_in + (size_t)node * 64))[s];   // self row slice
        acc0 = fmaf(dd, blo(zq.x), acc0);
        acc1 = fmaf(dd, bhi(zq.x), acc1);
        acc2 = fmaf(dd, blo(zq.y), acc2);
        acc3 = fmaf(dd, bhi(zq.y), acc3);
        acc4 = fmaf(dd, blo(zq.z), acc4);
        acc5 = fmaf(dd, bhi(zq.z), acc5);
        acc6 = fmaf(dd, blo(zq.w), acc6);
        acc7 = fmaf(dd, bhi(zq.w), acc7);
        if (MODE == 0) {
            uint4 xq = ((const uint4*)(x_bf + (size_t)node * 64))[s];
            uint4 o;
            o.x = pk2(acc0 + blo(xq.x), acc1 + bhi(xq.x));
            o.y = pk2(acc2 + blo(xq.y), acc3 + bhi(xq.y));
            o.z = pk2(acc4 + blo(xq.z), acc5 + bhi(xq.z));
            o.w = pk2(acc6 + blo(xq.w), acc7 + bhi(xq.w));
            ((uint4*)(z_out + (size_t)node * 64))[s] = o;
        } else {
            const float4* xr = (const float4*)(x + (size_t)node * 64);
            float4 xa = xr[s * 2], xb = xr[s * 2 + 1];
            float4* yr = (float4*)(y + (size_t)node * 64);
            yr[s * 2]     = make_float4(fmaf(0.09f, acc0, 0.1f * xa.x),
                                        fmaf(0.09f, acc1, 0.1f * xa.y),
                                        fmaf(0.09f, acc2, 0.1f * xa.z),
                                        fmaf(0.09f, acc3, 0.1f * xa.w));
            yr[s * 2 + 1] = make_float4(fmaf(0.09f, acc4, 0.1f * xb.x),
                                        fmaf(0.09f, acc5, 0.1f * xb.y),
                                        fmaf(0.09f, acc6, 0.1f * xb.z),
                                        fmaf(0.09f, acc7, 0.1f * xb.w));
        }
    }
}

// ---------------- MLP epilogue: y @ W0 relu @ W1 ----------------

__global__ __launch_bounds__(256) void mlp_k(const float* __restrict__ y,
                                             const float* __restrict__ W0,
                                             const float* __restrict__ b0,
                                             const float* __restrict__ W1,
                                             const float* __restrict__ b1,
                                             float* __restrict__ out, int n) {
    __shared__ float W0s[64 * 64];
    __shared__ float W1s[64 * 32];
    __shared__ float b0s[64];
    __shared__ float b1s[32];
    __shared__ float z[32][64];
    __shared__ float hid[32][64];
    int tid = threadIdx.x;
    for (int i = tid; i < 64 * 64; i += 256) W0s[i] = W0[i];
    for (int i = tid; i < 64 * 32; i += 256) W1s[i] = W1[i];
    if (tid < 64) b0s[tid] = b0[tid];
    else if (tid < 96) b1s[tid - 64] = b1[tid - 64];

    int base = blockIdx.x * 32;
    for (int r = 0; r < 8; ++r) {
        int idx = r * 256 + tid;
        int nn = idx >> 6, f = idx & 63;
        int node = base + nn;
        z[nn][f] = (node < n) ? y[(size_t)node * 64 + f] : 0.f;
    }
    __syncthreads();
    for (int r = 0; r < 8; ++r) {
        int idx = r * 256 + tid;
        int nn = idx >> 6, j = idx & 63;
        float s = b0s[j];
#pragma unroll
        for (int i = 0; i < 64; ++i) s += z[nn][i] * W0s[i * 64 + j];
        hid[nn][j] = fmaxf(s, 0.f);
    }
    __syncthreads();
    for (int r = 0; r < 4; ++r) {
        int idx = r * 256 + tid;
        int nn = idx >> 5, o = idx & 31;
        int node = base + nn;
        if (node >= n) continue;
        float s = b1s[o];
#pragma unroll
        for (int i = 0; i < 64; ++i) s += hid[nn][i] * W1s[i * 32 + o];
        out[(size_t)node * 32 + o] = s;
    }
}

// ---------------- launch ----------------

extern "C" void kernel_launch(void* const* d_in, const int* in_sizes, int n_in,
                              void* d_out, int out_size, void* d_ws, size_t ws_size,
                              hipStream_t stream) {
    const float* x   = (const float*)d_in[0];
    const int*   ei  = (const int*)d_in[1];
    const float* ew  = (const float*)d_in[2];
    const float* W0  = (const float*)d_in[3];
    const float* b0  = (const float*)d_in[4];
    const float* W1  = (const float*)d_in[5];
    const float* b1  = (const float*)d_in[6];
    float* out = (float*)d_out;

    const int N = in_sizes[0] / 64;   // 100000
    const int E = in_sizes[2];        // 1200000
    const int* row = ei;
    const int* col = ei + E;

    char* p = (char*)d_ws;
    auto alloc = [&](size_t bytes) -> void* {
        void* r = (void*)p;
        p += (bytes + 255) & ~(size_t)255;
        return r;
    };
    float* dinv      = (float*)alloc((size_t)N * 4);
    int*   counts    = (int*)alloc((size_t)N * 4);
    int*   offsets   = (int*)alloc((size_t)(N + 1) * 4);
    int    nb        = (N + 255) / 256;
    int*   blockSums = (int*)alloc((size_t)nb * 4);
    int*   pos       = (int*)alloc((size_t)E * 4);
    int2*  csr       = (int2*)alloc((size_t)E * 8);
    unsigned short* xbf = (unsigned short*)alloc((size_t)N * 64 * 2);  // bf16(x) == z0
    unsigned short* zA  = (unsigned short*)alloc((size_t)N * 64 * 2);
    unsigned short* zB  = (unsigned short*)alloc((size_t)N * 64 * 2);
    float* yv        = (float*)alloc((size_t)N * 64 * 4);

    int gN = (N + NTHREADS - 1) / NTHREADS;
    int gE = (E + NTHREADS - 1) / NTHREADS;

    deg_init_k<<<gN, NTHREADS, 0, stream>>>(dinv, counts, N);
    edge_pass1_k<<<gE, NTHREADS, 0, stream>>>(row, col, ew, dinv, counts, pos, E);
    dinv_k<<<gN, NTHREADS, 0, stream>>>(dinv, N);

    scan1_k<<<nb, 256, 0, stream>>>(counts, offsets, blockSums, N);
    scan2_k<<<1, 1024, 0, stream>>>(blockSums, nb);
    scan3_k<<<(N + 1 + NTHREADS - 1) / NTHREADS, NTHREADS, 0, stream>>>(offsets, blockSums, N, E);
    scatter_k<<<gE, NTHREADS, 0, stream>>>(row, col, ew, dinv, offsets, pos, csr, E);

    tobf16_k<<<(N * 64 + NTHREADS - 1) / NTHREADS, NTHREADS, 0, stream>>>(x, xbf, N * 64);

    // 9 Horner steps: z_j = bf16(x + A z_{j-1}); first input is xbf (= z0)
    int gP = (N + 3) / 4;
    const unsigned short* zi = xbf;
    for (int k = 1; k <= 9; ++k) {
        unsigned short* zo = (zi == zA) ? zB : zA;
        horner8_k<0><<<gP, 256, 0, stream>>>(zi, zo, nullptr, xbf, x, dinv, offsets, csr, N);
        zi = zo;
    }
    // final: y = 0.09 * (A z_9) + 0.1 * x
    horner8_k<1><<<gP, 256, 0, stream>>>(zi, nullptr, yv, xbf, x, dinv, offsets, csr, N);

    mlp_k<<<(N + 31) / 32, 256, 0, stream>>>(yv, W0, b0, W1, b1, out, N);
}

// Round 5
// 575.604 us; speedup vs baseline: 2.4316x; 1.0872x over previous
//
#include <hip/hip_runtime.h>
#include <hip/hip_bf16.h>

#define NTHREADS 256

typedef unsigned int uint32;

// ---------------- bf16 helpers ----------------

__device__ __forceinline__ float blo(uint32 u) { return __uint_as_float(u << 16); }
__device__ __forceinline__ float bhi(uint32 u) { return __uint_as_float(u & 0xffff0000u); }

__device__ __forceinline__ unsigned short bf16bits(float f) {
    __hip_bfloat16 h = __float2bfloat16(f);
    return *reinterpret_cast<unsigned short*>(&h);
}
__device__ __forceinline__ uint32 pk2(float a, float b) {
    return (uint32)bf16bits(a) | ((uint32)bf16bits(b) << 16);
}

// ---------------- degree + count + slot: one fused edge pass ----------------

__global__ void deg_init_k(float* deg, int* counts, int n) {
    int i = blockIdx.x * blockDim.x + threadIdx.x;
    if (i < n) { deg[i] = 1.0f; counts[i] = 0; }   // self-loop weight 1
}

__global__ void edge_pass1_k(const int* __restrict__ row, const int* __restrict__ col,
                             const float* __restrict__ w, float* deg, int* counts,
                             int* __restrict__ pos, int e) {
    int i = blockIdx.x * blockDim.x + threadIdx.x;
    if (i < e) {
        atomicAdd(&deg[row[i]], w[i]);
        pos[i] = atomicAdd(&counts[col[i]], 1);   // slot within destination node
    }
}

__global__ void dinv_k(float* deg, int n) {
    int i = blockIdx.x * blockDim.x + threadIdx.x;
    if (i < n) deg[i] = rsqrtf(fmaxf(deg[i], 1e-12f));   // in-place: deg -> dinv
}

// ---------------- CSR offsets (scan over counts) ----------------

__global__ void scan1_k(const int* __restrict__ counts, int* offsets, int* blockSums, int n) {
    __shared__ int s[256];
    int tid = threadIdx.x;
    int idx = blockIdx.x * 256 + tid;
    int v = (idx < n) ? counts[idx] : 0;
    s[tid] = v;
    __syncthreads();
    for (int off = 1; off < 256; off <<= 1) {
        int t = (tid >= off) ? s[tid - off] : 0;
        __syncthreads();
        s[tid] += t;
        __syncthreads();
    }
    if (idx < n) offsets[idx] = s[tid] - v;
    if (tid == 255) blockSums[blockIdx.x] = s[255];
}

__global__ void scan2_k(int* blockSums, int nb) {
    __shared__ int s[1024];
    int tid = threadIdx.x;
    int v = (tid < nb) ? blockSums[tid] : 0;
    s[tid] = v;
    __syncthreads();
    for (int off = 1; off < 1024; off <<= 1) {
        int t = (tid >= off) ? s[tid - off] : 0;
        __syncthreads();
        s[tid] += t;
        __syncthreads();
    }
    if (tid < nb) blockSums[tid] = s[tid] - v;
}

__global__ void scan3_k(int* offsets, const int* __restrict__ blockSums, int n, int total) {
    int idx = blockIdx.x * blockDim.x + threadIdx.x;
    if (idx < n) offsets[idx] += blockSums[idx >> 8];
    if (idx == n) offsets[n] = total;
}

// ---------------- atomic-free scatter ----------------

__global__ void scatter_k(const int* __restrict__ row, const int* __restrict__ col,
                          const float* __restrict__ w, const float* __restrict__ dinv,
                          const int* __restrict__ offsets, const int* __restrict__ pos,
                          int2* __restrict__ csr, int e) {
    int i = blockIdx.x * blockDim.x + threadIdx.x;
    if (i >= e) return;
    int r = row[i], c = col[i];
    int p = offsets[c] + pos[i];
    float nw = dinv[r] * w[i] * dinv[c];
    csr[p] = make_int2(r, __float_as_int(nw));
}

// ---------------- x -> bf16 seed (2 floats / thread) ----------------

__global__ void tobf16_k(const float* __restrict__ x, uint32* __restrict__ z, int pairs) {
    int i = blockIdx.x * blockDim.x + threadIdx.x;
    if (i < pairs) {
        float2 v = ((const float2*)x)[i];
        z[i] = pk2(v.x, v.y);
    }
}

// ---------------- Horner propagation: 4 nodes per wave, interleaved ILP ----------------
// Wave: 8 groups (g) x 8 lanes (s). Per loop iter: 4 independent csr loads + 4
// independent 128B row gathers (one per node) -> 4 parallel latency chains.
// Tail: group m (m<4) finalizes node m.
// MODE 0: z_out = bf16( x_bf + A * z_in )
// MODE 1: ybf   = bf16( 0.09f * (A * z_in) + 0.1f * x )

template <int MODE>
__global__ __launch_bounds__(256) void horner4n_k(
    const unsigned short* __restrict__ z_in,
    unsigned short* __restrict__ z_out,
    unsigned short* __restrict__ ybf,
    const unsigned short* __restrict__ x_bf,
    const float* __restrict__ x,
    const float* __restrict__ dinv,
    const int* __restrict__ offsets,
    const int2* __restrict__ csr,
    int n)
{
    int wv = __builtin_amdgcn_readfirstlane(threadIdx.x >> 6);
    int lane = threadIdx.x & 63;
    int g = lane >> 3;   // group
    int s = lane & 7;    // 16B slice of a 128B bf16 row
    int nbase = blockIdx.x * 16 + wv * 4;

    int bb[4], ee[4];
#pragma unroll
    for (int m = 0; m < 4; ++m) {
        int node = nbase + m;
        if (node < n) { bb[m] = offsets[node]; ee[m] = offsets[node + 1]; }
        else          { bb[m] = 0; ee[m] = 0; }
    }
    int d0 = ee[0] - bb[0], d1 = ee[1] - bb[1], d2 = ee[2] - bb[2], d3 = ee[3] - bb[3];
    int maxd = max(max(d0, d1), max(d2, d3));

    float acc[4][8];
#pragma unroll
    for (int m = 0; m < 4; ++m)
#pragma unroll
        for (int i = 0; i < 8; ++i) acc[m][i] = 0.f;

    for (int off = 0; off < maxd; off += 8) {
        int2 sw[4];
#pragma unroll
        for (int m = 0; m < 4; ++m) {
            int j = bb[m] + off + g;
            sw[m] = (j < ee[m]) ? csr[j] : make_int2(0, 0);
        }
        uint4 q[4];
#pragma unroll
        for (int m = 0; m < 4; ++m)
            q[m] = ((const uint4*)(z_in + (size_t)sw[m].x * 64))[s];
#pragma unroll
        for (int m = 0; m < 4; ++m) {
            float w = __int_as_float(sw[m].y);
            acc[m][0] = fmaf(w, blo(q[m].x), acc[m][0]);
            acc[m][1] = fmaf(w, bhi(q[m].x), acc[m][1]);
            acc[m][2] = fmaf(w, blo(q[m].y), acc[m][2]);
            acc[m][3] = fmaf(w, bhi(q[m].y), acc[m][3]);
            acc[m][4] = fmaf(w, blo(q[m].z), acc[m][4]);
            acc[m][5] = fmaf(w, bhi(q[m].z), acc[m][5]);
            acc[m][6] = fmaf(w, blo(q[m].w), acc[m][6]);
            acc[m][7] = fmaf(w, bhi(q[m].w), acc[m][7]);
        }
    }

    // butterfly across the 8 groups (lane bits 3,4,5): every lane gets full sums
#pragma unroll
    for (int mask = 8; mask <= 32; mask <<= 1)
#pragma unroll
        for (int m = 0; m < 4; ++m)
#pragma unroll
            for (int i = 0; i < 8; ++i)
                acc[m][i] += __shfl_xor(acc[m][i], mask);

    // select node-g's sums with a static-index cndmask tree (no scratch)
    float t[8];
#pragma unroll
    for (int i = 0; i < 8; ++i) {
        float a01 = (g == 0) ? acc[0][i] : acc[1][i];
        float a23 = (g == 2) ? acc[2][i] : acc[3][i];
        t[i] = (g < 2) ? a01 : a23;
    }

    if (g < 4) {
        int node = nbase + g;
        if (node < n) {
            float di = dinv[node];
            float dd = di * di;
            uint4 zq = ((const uint4*)(z_in + (size_t)node * 64))[s];  // self row slice
            t[0] = fmaf(dd, blo(zq.x), t[0]);
            t[1] = fmaf(dd, bhi(zq.x), t[1]);
            t[2] = fmaf(dd, blo(zq.y), t[2]);
            t[3] = fmaf(dd, bhi(zq.y), t[3]);
            t[4] = fmaf(dd, blo(zq.z), t[4]);
            t[5] = fmaf(dd, bhi(zq.z), t[5]);
            t[6] = fmaf(dd, blo(zq.w), t[6]);
            t[7] = fmaf(dd, bhi(zq.w), t[7]);
            if (MODE == 0) {
                uint4 xq = ((const uint4*)(x_bf + (size_t)node * 64))[s];
                uint4 o;
                o.x = pk2(t[0] + blo(xq.x), t[1] + bhi(xq.x));
                o.y = pk2(t[2] + blo(xq.y), t[3] + bhi(xq.y));
                o.z = pk2(t[4] + blo(xq.z), t[5] + bhi(xq.z));
                o.w = pk2(t[6] + blo(xq.w), t[7] + bhi(xq.w));
                ((uint4*)(z_out + (size_t)node * 64))[s] = o;
            } else {
                const float4* xr = (const float4*)(x + (size_t)node * 64);
                float4 xa = xr[s * 2], xb = xr[s * 2 + 1];
                uint4 o;
                o.x = pk2(fmaf(0.09f, t[0], 0.1f * xa.x), fmaf(0.09f, t[1], 0.1f * xa.y));
                o.y = pk2(fmaf(0.09f, t[2], 0.1f * xa.z), fmaf(0.09f, t[3], 0.1f * xa.w));
                o.z = pk2(fmaf(0.09f, t[4], 0.1f * xb.x), fmaf(0.09f, t[5], 0.1f * xb.y));
                o.w = pk2(fmaf(0.09f, t[6], 0.1f * xb.z), fmaf(0.09f, t[7], 0.1f * xb.w));
                ((uint4*)(ybf + (size_t)node * 64))[s] = o;
            }
        }
    }
}

// ---------------- MLP epilogue: y @ W0 relu @ W1 (y in bf16) ----------------

__global__ __launch_bounds__(256) void mlp_k(const unsigned short* __restrict__ ybf,
                                             const float* __restrict__ W0,
                                             const float* __restrict__ b0,
                                             const float* __restrict__ W1,
                                             const float* __restrict__ b1,
                                             float* __restrict__ out, int n) {
    __shared__ float W0s[64 * 64];
    __shared__ float W1s[64 * 32];
    __shared__ float b0s[64];
    __shared__ float b1s[32];
    __shared__ float z[32][64];
    __shared__ float hid[32][64];
    int tid = threadIdx.x;
    for (int i = tid; i < 64 * 64; i += 256) W0s[i] = W0[i];
    for (int i = tid; i < 64 * 32; i += 256) W1s[i] = W1[i];
    if (tid < 64) b0s[tid] = b0[tid];
    else if (tid < 96) b1s[tid - 64] = b1[tid - 64];

    int base = blockIdx.x * 32;
    const uint32* y32 = (const uint32*)ybf;
    for (int r = 0; r < 4; ++r) {
        int idx = r * 256 + tid;       // 1024 uints = 32 nodes x 32 uints
        int nn = idx >> 5, f2 = idx & 31;
        int node = base + nn;
        uint32 v = (node < n) ? y32[(size_t)node * 32 + f2] : 0u;
        z[nn][f2 * 2]     = blo(v);
        z[nn][f2 * 2 + 1] = bhi(v);
    }
    __syncthreads();
    for (int r = 0; r < 8; ++r) {
        int idx = r * 256 + tid;
        int nn = idx >> 6, j = idx & 63;
        float s = b0s[j];
#pragma unroll
        for (int i = 0; i < 64; ++i) s += z[nn][i] * W0s[i * 64 + j];
        hid[nn][j] = fmaxf(s, 0.f);
    }
    __syncthreads();
    for (int r = 0; r < 4; ++r) {
        int idx = r * 256 + tid;
        int nn = idx >> 5, o = idx & 31;
        int node = base + nn;
        if (node >= n) continue;
        float s = b1s[o];
#pragma unroll
        for (int i = 0; i < 64; ++i) s += hid[nn][i] * W1s[i * 32 + o];
        out[(size_t)node * 32 + o] = s;
    }
}

// ---------------- launch ----------------

extern "C" void kernel_launch(void* const* d_in, const int* in_sizes, int n_in,
                              void* d_out, int out_size, void* d_ws, size_t ws_size,
                              hipStream_t stream) {
    const float* x   = (const float*)d_in[0];
    const int*   ei  = (const int*)d_in[1];
    const float* ew  = (const float*)d_in[2];
    const float* W0  = (const float*)d_in[3];
    const float* b0  = (const float*)d_in[4];
    const float* W1  = (const float*)d_in[5];
    const float* b1  = (const float*)d_in[6];
    float* out = (float*)d_out;

    const int N = in_sizes[0] / 64;   // 100000
    const int E = in_sizes[2];        // 1200000
    const int* row = ei;
    const int* col = ei + E;

    char* p = (char*)d_ws;
    auto alloc = [&](size_t bytes) -> void* {
        void* r = (void*)p;
        p += (bytes + 255) & ~(size_t)255;
        return r;
    };
    float* dinv      = (float*)alloc((size_t)N * 4);
    int*   counts    = (int*)alloc((size_t)N * 4);
    int*   offsets   = (int*)alloc((size_t)(N + 1) * 4);
    int    nb        = (N + 255) / 256;
    int*   blockSums = (int*)alloc((size_t)nb * 4);
    int*   pos       = (int*)alloc((size_t)E * 4);
    int2*  csr       = (int2*)alloc((size_t)E * 8);
    unsigned short* xbf = (unsigned short*)alloc((size_t)N * 64 * 2);  // bf16(x) == z0
    unsigned short* zA  = (unsigned short*)alloc((size_t)N * 64 * 2);
    unsigned short* zB  = (unsigned short*)alloc((size_t)N * 64 * 2);
    unsigned short* ybf = (unsigned short*)alloc((size_t)N * 64 * 2);

    int gN = (N + NTHREADS - 1) / NTHREADS;
    int gE = (E + NTHREADS - 1) / NTHREADS;

    deg_init_k<<<gN, NTHREADS, 0, stream>>>(dinv, counts, N);
    edge_pass1_k<<<gE, NTHREADS, 0, stream>>>(row, col, ew, dinv, counts, pos, E);
    dinv_k<<<gN, NTHREADS, 0, stream>>>(dinv, N);

    scan1_k<<<nb, 256, 0, stream>>>(counts, offsets, blockSums, N);
    scan2_k<<<1, 1024, 0, stream>>>(blockSums, nb);
    scan3_k<<<(N + 1 + NTHREADS - 1) / NTHREADS, NTHREADS, 0, stream>>>(offsets, blockSums, N, E);
    scatter_k<<<gE, NTHREADS, 0, stream>>>(row, col, ew, dinv, offsets, pos, csr, E);

    int pairs = N * 32;
    tobf16_k<<<(pairs + NTHREADS - 1) / NTHREADS, NTHREADS, 0, stream>>>(x, (uint32*)xbf, pairs);

    // 9 Horner steps: z_j = bf16(x + A z_{j-1}); first input is xbf (= z0)
    int gP = (N + 15) / 16;
    const unsigned short* zi = xbf;
    for (int k = 1; k <= 9; ++k) {
        unsigned short* zo = (zi == zA) ? zB : zA;
        horner4n_k<0><<<gP, 256, 0, stream>>>(zi, zo, nullptr, xbf, x, dinv, offsets, csr, N);
        zi = zo;
    }
    // final: ybf = bf16(0.09 * (A z_9) + 0.1 * x)
    horner4n_k<1><<<gP, 256, 0, stream>>>(zi, nullptr, ybf, xbf, x, dinv, offsets, csr, N);

    mlp_k<<<(N + 31) / 32, 256, 0, stream>>>(ybf, W0, b0, W1, b1, out, N);
}

// Round 6
// 535.981 us; speedup vs baseline: 2.6114x; 1.0739x over previous
//
#include <hip/hip_runtime.h>
#include <hip/hip_bf16.h>

#define NTHREADS 256

typedef unsigned int uint32;

// ---------------- bf16 helpers ----------------

__device__ __forceinline__ float blo(uint32 u) { return __uint_as_float(u << 16); }
__device__ __forceinline__ float bhi(uint32 u) { return __uint_as_float(u & 0xffff0000u); }

__device__ __forceinline__ unsigned short bf16bits(float f) {
    __hip_bfloat16 h = __float2bfloat16(f);
    return *reinterpret_cast<unsigned short*>(&h);
}
__device__ __forceinline__ uint32 pk2(float a, float b) {
    return (uint32)bf16bits(a) | ((uint32)bf16bits(b) << 16);
}

// ---------------- degree + count + slot: one fused edge pass ----------------

__global__ void deg_init_k(float* deg, int* counts, int n) {
    int i = blockIdx.x * blockDim.x + threadIdx.x;
    if (i < n) { deg[i] = 1.0f; counts[i] = 0; }   // self-loop weight 1
}

__global__ void edge_pass1_k(const int* __restrict__ row, const int* __restrict__ col,
                             const float* __restrict__ w, float* deg, int* counts,
                             int* __restrict__ pos, int e) {
    int i = blockIdx.x * blockDim.x + threadIdx.x;
    if (i < e) {
        unsafeAtomicAdd(&deg[row[i]], w[i]);      // native global_atomic_add_f32
        pos[i] = atomicAdd(&counts[col[i]], 1);   // slot within destination node
    }
}

__global__ void dinv_k(float* deg, int n) {
    int i = blockIdx.x * blockDim.x + threadIdx.x;
    if (i < n) deg[i] = rsqrtf(fmaxf(deg[i], 1e-12f));   // in-place: deg -> dinv
}

// ---------------- CSR offsets (scan over counts) ----------------

__global__ void scan1_k(const int* __restrict__ counts, int* offsets, int* blockSums, int n) {
    __shared__ int s[256];
    int tid = threadIdx.x;
    int idx = blockIdx.x * 256 + tid;
    int v = (idx < n) ? counts[idx] : 0;
    s[tid] = v;
    __syncthreads();
    for (int off = 1; off < 256; off <<= 1) {
        int t = (tid >= off) ? s[tid - off] : 0;
        __syncthreads();
        s[tid] += t;
        __syncthreads();
    }
    if (idx < n) offsets[idx] = s[tid] - v;
    if (tid == 255) blockSums[blockIdx.x] = s[255];
}

__global__ void scan2_k(int* blockSums, int nb) {
    __shared__ int s[1024];
    int tid = threadIdx.x;
    int v = (tid < nb) ? blockSums[tid] : 0;
    s[tid] = v;
    __syncthreads();
    for (int off = 1; off < 1024; off <<= 1) {
        int t = (tid >= off) ? s[tid - off] : 0;
        __syncthreads();
        s[tid] += t;
        __syncthreads();
    }
    if (tid < nb) blockSums[tid] = s[tid] - v;
}

__global__ void scan3_k(int* offsets, const int* __restrict__ blockSums, int n, int total) {
    int idx = blockIdx.x * blockDim.x + threadIdx.x;
    if (idx < n) offsets[idx] += blockSums[idx >> 8];
    if (idx == n) offsets[n] = total;
}

// ---------------- atomic-free scatter: csr = (src, RAW w) — no dinv ----------------

__global__ void scatter_k(const int* __restrict__ row, const int* __restrict__ col,
                          const float* __restrict__ w,
                          const int* __restrict__ offsets, const int* __restrict__ pos,
                          int2* __restrict__ csr, int e) {
    int i = blockIdx.x * blockDim.x + threadIdx.x;
    if (i >= e) return;
    int p = offsets[col[i]] + pos[i];
    csr[p] = make_int2(row[i], __float_as_int(w[i]));
}

// ---------------- u-seed: ux = bf16(dinv * x), 2 floats / thread ----------------

__global__ void uxseed_k(const float* __restrict__ x, const float* __restrict__ dinv,
                         uint32* __restrict__ ux, int pairs) {
    int i = blockIdx.x * blockDim.x + threadIdx.x;
    if (i < pairs) {
        float di = dinv[i >> 5];          // 32 pairs per node
        float2 v = ((const float2*)x)[i];
        ux[i] = pk2(di * v.x, di * v.y);
    }
}

// ---------------- Horner in u-space: 4 nodes per wave, csr-prefetch pipeline ----------------
// u = D^-1/2 z.  u_j = ux + dd * (W u_{j-1}),  (W u)[c] = u[c] + sum_e w_e u[src_e]
// MODE 0: u_out = bf16( ux + dd * (W u_in) )
// MODE 1: ybf   = bf16( 0.09*dinv*(W u_in) + 0.1*x )

template <int MODE>
__global__ __launch_bounds__(256) void horner4n_k(
    const unsigned short* __restrict__ u_in,
    unsigned short* __restrict__ u_out,
    unsigned short* __restrict__ ybf,
    const unsigned short* __restrict__ ux_bf,
    const float* __restrict__ x,
    const float* __restrict__ dinv,
    const int* __restrict__ offsets,
    const int2* __restrict__ csr,
    int n)
{
    int wv = __builtin_amdgcn_readfirstlane(threadIdx.x >> 6);
    int lane = threadIdx.x & 63;
    int g = lane >> 3;   // group
    int s = lane & 7;    // 16B slice of a 128B bf16 row
    int nbase = blockIdx.x * 16 + wv * 4;

    int bb[4], ee[4];
#pragma unroll
    for (int m = 0; m < 4; ++m) {
        int node = nbase + m;
        if (node < n) { bb[m] = offsets[node]; ee[m] = offsets[node + 1]; }
        else          { bb[m] = 0; ee[m] = 0; }
    }
    int maxd = max(max(ee[0] - bb[0], ee[1] - bb[1]), max(ee[2] - bb[2], ee[3] - bb[3]));

    float acc[4][8];
#pragma unroll
    for (int m = 0; m < 4; ++m)
#pragma unroll
        for (int i = 0; i < 8; ++i) acc[m][i] = 0.f;

    // prologue: load first csr batch
    int2 sw[4];
#pragma unroll
    for (int m = 0; m < 4; ++m) {
        int j = bb[m] + g;
        sw[m] = (j < ee[m]) ? csr[j] : make_int2(0, 0);
    }

    for (int off = 0; off < maxd; off += 8) {
        // issue gathers for current batch
        uint4 q[4];
#pragma unroll
        for (int m = 0; m < 4; ++m)
            q[m] = ((const uint4*)(u_in + (size_t)sw[m].x * 64))[s];
        // prefetch next csr batch (overlaps with gathers)
        int2 swn[4];
#pragma unroll
        for (int m = 0; m < 4; ++m) {
            int j = bb[m] + off + 8 + g;
            swn[m] = (j < ee[m]) ? csr[j] : make_int2(0, 0);
        }
        // consume gathers
#pragma unroll
        for (int m = 0; m < 4; ++m) {
            float w = __int_as_float(sw[m].y);
            acc[m][0] = fmaf(w, blo(q[m].x), acc[m][0]);
            acc[m][1] = fmaf(w, bhi(q[m].x), acc[m][1]);
            acc[m][2] = fmaf(w, blo(q[m].y), acc[m][2]);
            acc[m][3] = fmaf(w, bhi(q[m].y), acc[m][3]);
            acc[m][4] = fmaf(w, blo(q[m].z), acc[m][4]);
            acc[m][5] = fmaf(w, bhi(q[m].z), acc[m][5]);
            acc[m][6] = fmaf(w, blo(q[m].w), acc[m][6]);
            acc[m][7] = fmaf(w, bhi(q[m].w), acc[m][7]);
        }
#pragma unroll
        for (int m = 0; m < 4; ++m) sw[m] = swn[m];
    }

    // butterfly across the 8 groups (lane bits 3,4,5)
#pragma unroll
    for (int mask = 8; mask <= 32; mask <<= 1)
#pragma unroll
        for (int m = 0; m < 4; ++m)
#pragma unroll
            for (int i = 0; i < 8; ++i)
                acc[m][i] += __shfl_xor(acc[m][i], mask);

    // select node-g's sums with a static-index cndmask tree (no scratch)
    float t[8];
#pragma unroll
    for (int i = 0; i < 8; ++i) {
        float a01 = (g == 0) ? acc[0][i] : acc[1][i];
        float a23 = (g == 2) ? acc[2][i] : acc[3][i];
        t[i] = (g < 2) ? a01 : a23;
    }

    if (g < 4) {
        int node = nbase + g;
        if (node < n) {
            float di = dinv[node];
            uint4 zq = ((const uint4*)(u_in + (size_t)node * 64))[s];  // self u-row slice
            t[0] += blo(zq.x); t[1] += bhi(zq.x);
            t[2] += blo(zq.y); t[3] += bhi(zq.y);
            t[4] += blo(zq.z); t[5] += bhi(zq.z);
            t[6] += blo(zq.w); t[7] += bhi(zq.w);
            if (MODE == 0) {
                float dd = di * di;
                uint4 xq = ((const uint4*)(ux_bf + (size_t)node * 64))[s];
                uint4 o;
                o.x = pk2(fmaf(dd, t[0], blo(xq.x)), fmaf(dd, t[1], bhi(xq.x)));
                o.y = pk2(fmaf(dd, t[2], blo(xq.y)), fmaf(dd, t[3], bhi(xq.y)));
                o.z = pk2(fmaf(dd, t[4], blo(xq.z)), fmaf(dd, t[5], bhi(xq.z)));
                o.w = pk2(fmaf(dd, t[6], blo(xq.w)), fmaf(dd, t[7], bhi(xq.w)));
                ((uint4*)(u_out + (size_t)node * 64))[s] = o;
            } else {
                float c = 0.09f * di;
                const float4* xr = (const float4*)(x + (size_t)node * 64);
                float4 xa = xr[s * 2], xb = xr[s * 2 + 1];
                uint4 o;
                o.x = pk2(fmaf(c, t[0], 0.1f * xa.x), fmaf(c, t[1], 0.1f * xa.y));
                o.y = pk2(fmaf(c, t[2], 0.1f * xa.z), fmaf(c, t[3], 0.1f * xa.w));
                o.z = pk2(fmaf(c, t[4], 0.1f * xb.x), fmaf(c, t[5], 0.1f * xb.y));
                o.w = pk2(fmaf(c, t[6], 0.1f * xb.z), fmaf(c, t[7], 0.1f * xb.w));
                ((uint4*)(ybf + (size_t)node * 64))[s] = o;
            }
        }
    }
}

// ---------------- MLP epilogue: y @ W0 relu @ W1 (y in bf16) ----------------

__global__ __launch_bounds__(256) void mlp_k(const unsigned short* __restrict__ ybf,
                                             const float* __restrict__ W0,
                                             const float* __restrict__ b0,
                                             const float* __restrict__ W1,
                                             const float* __restrict__ b1,
                                             float* __restrict__ out, int n) {
    __shared__ float W0s[64 * 64];
    __shared__ float W1s[64 * 32];
    __shared__ float b0s[64];
    __shared__ float b1s[32];
    __shared__ float z[32][64];
    __shared__ float hid[32][64];
    int tid = threadIdx.x;
    for (int i = tid; i < 64 * 64; i += 256) W0s[i] = W0[i];
    for (int i = tid; i < 64 * 32; i += 256) W1s[i] = W1[i];
    if (tid < 64) b0s[tid] = b0[tid];
    else if (tid < 96) b1s[tid - 64] = b1[tid - 64];

    int base = blockIdx.x * 32;
    const uint32* y32 = (const uint32*)ybf;
    for (int r = 0; r < 4; ++r) {
        int idx = r * 256 + tid;       // 1024 uints = 32 nodes x 32 uints
        int nn = idx >> 5, f2 = idx & 31;
        int node = base + nn;
        uint32 v = (node < n) ? y32[(size_t)node * 32 + f2] : 0u;
        z[nn][f2 * 2]     = blo(v);
        z[nn][f2 * 2 + 1] = bhi(v);
    }
    __syncthreads();
    for (int r = 0; r < 8; ++r) {
        int idx = r * 256 + tid;
        int nn = idx >> 6, j = idx & 63;
        float s = b0s[j];
#pragma unroll
        for (int i = 0; i < 64; ++i) s += z[nn][i] * W0s[i * 64 + j];
        hid[nn][j] = fmaxf(s, 0.f);
    }
    __syncthreads();
    for (int r = 0; r < 4; ++r) {
        int idx = r * 256 + tid;
        int nn = idx >> 5, o = idx & 31;
        int node = base + nn;
        if (node >= n) continue;
        float s = b1s[o];
#pragma unroll
        for (int i = 0; i < 64; ++i) s += hid[nn][i] * W1s[i * 32 + o];
        out[(size_t)node * 32 + o] = s;
    }
}

// ---------------- launch ----------------

extern "C" void kernel_launch(void* const* d_in, const int* in_sizes, int n_in,
                              void* d_out, int out_size, void* d_ws, size_t ws_size,
                              hipStream_t stream) {
    const float* x   = (const float*)d_in[0];
    const int*   ei  = (const int*)d_in[1];
    const float* ew  = (const float*)d_in[2];
    const float* W0  = (const float*)d_in[3];
    const float* b0  = (const float*)d_in[4];
    const float* W1  = (const float*)d_in[5];
    const float* b1  = (const float*)d_in[6];
    float* out = (float*)d_out;

    const int N = in_sizes[0] / 64;   // 100000
    const int E = in_sizes[2];        // 1200000
    const int* row = ei;
    const int* col = ei + E;

    char* p = (char*)d_ws;
    auto alloc = [&](size_t bytes) -> void* {
        void* r = (void*)p;
        p += (bytes + 255) & ~(size_t)255;
        return r;
    };
    float* dinv      = (float*)alloc((size_t)N * 4);
    int*   counts    = (int*)alloc((size_t)N * 4);
    int*   offsets   = (int*)alloc((size_t)(N + 1) * 4);
    int    nb        = (N + 255) / 256;
    int*   blockSums = (int*)alloc((size_t)nb * 4);
    int*   pos       = (int*)alloc((size_t)E * 4);
    int2*  csr       = (int2*)alloc((size_t)E * 8);
    unsigned short* uxbf = (unsigned short*)alloc((size_t)N * 64 * 2);  // dinv*x bf16 == u0
    unsigned short* uA   = (unsigned short*)alloc((size_t)N * 64 * 2);
    unsigned short* uB   = (unsigned short*)alloc((size_t)N * 64 * 2);
    unsigned short* ybf  = (unsigned short*)alloc((size_t)N * 64 * 2);

    int gN = (N + NTHREADS - 1) / NTHREADS;
    int gE = (E + NTHREADS - 1) / NTHREADS;

    deg_init_k<<<gN, NTHREADS, 0, stream>>>(dinv, counts, N);
    edge_pass1_k<<<gE, NTHREADS, 0, stream>>>(row, col, ew, dinv, counts, pos, E);
    dinv_k<<<gN, NTHREADS, 0, stream>>>(dinv, N);

    scan1_k<<<nb, 256, 0, stream>>>(counts, offsets, blockSums, N);
    scan2_k<<<1, 1024, 0, stream>>>(blockSums, nb);
    scan3_k<<<(N + 1 + NTHREADS - 1) / NTHREADS, NTHREADS, 0, stream>>>(offsets, blockSums, N, E);
    scatter_k<<<gE, NTHREADS, 0, stream>>>(row, col, ew, offsets, pos, csr, E);

    int pairs = N * 32;
    uxseed_k<<<(pairs + NTHREADS - 1) / NTHREADS, NTHREADS, 0, stream>>>(x, dinv,
                                                                         (uint32*)uxbf, pairs);

    // 9 Horner steps in u-space; first input is uxbf (= u0)
    int gP = (N + 15) / 16;
    const unsigned short* ui = uxbf;
    for (int k = 1; k <= 9; ++k) {
        unsigned short* uo = (ui == uA) ? uB : uA;
        horner4n_k<0><<<gP, 256, 0, stream>>>(ui, uo, nullptr, uxbf, x, dinv, offsets, csr, N);
        ui = uo;
    }
    // final: ybf = bf16(0.09*dinv*(W u_9) + 0.1*x)
    horner4n_k<1><<<gP, 256, 0, stream>>>(ui, nullptr, ybf, uxbf, x, dinv, offsets, csr, N);

    mlp_k<<<(N + 31) / 32, 256, 0, stream>>>(ybf, W0, b0, W1, b1, out, N);
}